// Round 1
// baseline (98.598 us; speedup 1.0000x reference)
//
#include <hip/hip_runtime.h>
#include <hip/hip_bf16.h>

// Problem: z = scatter_ones(zeros[32,6144,350], x[32,200,3]); out = z.reshape(32,-1) @ W + b
// Key identity: out[b,o] = sum over UNIQUE flat indices f=(i0*350+i1) in row b of W[f,o] + b[o].
// Only ~200 W rows (5 floats each) are touched per batch row -> pure gather, ~0.2 MB traffic.
// Duplicate (i0,i1) within a row must count ONCE (scatter .set semantics), so we dedup in LDS.

#define B_ROWS 32
#define NHITS  200
#define D1     350
#define OUT_N  5

__global__ __launch_bounds__(256) void prtnn_gather_kernel(
    const int* __restrict__ x,      // [32,200,3] int32
    const float* __restrict__ W,    // [2150400, 5] f32
    const float* __restrict__ bias, // [5] f32
    float* __restrict__ out)        // [32, 5] f32
{
    const int b = blockIdx.x;   // one block per batch row
    const int t = threadIdx.x;

    __shared__ int   flat_idx[NHITS];
    __shared__ float acc[OUT_N];

    if (t < OUT_N) acc[t] = 0.0f;

    if (t < NHITS) {
        const int* xp = x + (b * NHITS + t) * 3;
        const int i0 = xp[1];
        const int i1 = xp[2];
        flat_idx[t] = i0 * D1 + i1;
    }
    __syncthreads();

    if (t < NHITS) {
        const int f = flat_idx[t];
        // dedup: keep only the first occurrence of each flat index in this row
        bool dup = false;
        for (int j = 0; j < t; ++j) {
            if (flat_idx[j] == f) { dup = true; break; }
        }
        if (!dup) {
            const float* w = W + (size_t)f * OUT_N;
            #pragma unroll
            for (int o = 0; o < OUT_N; ++o) {
                atomicAdd(&acc[o], w[o]);
            }
        }
    }
    __syncthreads();

    if (t < OUT_N) {
        out[b * OUT_N + t] = acc[t] + bias[t];
    }
}

extern "C" void kernel_launch(void* const* d_in, const int* in_sizes, int n_in,
                              void* d_out, int out_size, void* d_ws, size_t ws_size,
                              hipStream_t stream) {
    const int*   x    = (const int*)d_in[0];     // [32,200,3]
    const float* W    = (const float*)d_in[1];   // [2150400,5]
    const float* bias = (const float*)d_in[2];   // [5]
    float*       out  = (float*)d_out;           // [32,5]

    prtnn_gather_kernel<<<B_ROWS, 256, 0, stream>>>(x, W, bias, out);
}

// Round 2
// 84.651 us; speedup vs baseline: 1.1648x; 1.1648x over previous
//
#include <hip/hip_runtime.h>
#include <hip/hip_bf16.h>

// Problem: z = scatter_ones(zeros[32,6144,350], x[32,200,3]); out = z.reshape(32,-1) @ W + b
// Identity: out[b,o] = sum over UNIQUE flat indices f=(i0*350+i1) in row b of W[f,o] + b[o].
// Only ~200 W rows (5 floats) touched per batch row -> pure gather (~128 KB of W total).
// Duplicate (i0,i1) within a row counts ONCE (scatter .set semantics) -> dedup in LDS.
//
// R1 changes vs R0 (theory: kill serial chains):
//  - x staged via coalesced int4 loads (was stride-12 scalar)
//  - dedup: wave-uniform full loop over LDS (broadcast reads, pipelined, unroll 8)
//    instead of per-lane early-exit serial chain (~200 x 120cyc dependent ds_reads)
//  - reduction: __shfl_down wave reduce + 4x5 LDS partials (was 1000 contended LDS atomics)

#define B_ROWS 32
#define NHITS  200
#define D1     350
#define OUT_N  5

__global__ __launch_bounds__(256) void prtnn_gather_kernel(
    const int* __restrict__ x,      // [32,200,3] int32
    const float* __restrict__ W,    // [2150400, 5] f32
    const float* __restrict__ bias, // [5] f32
    float* __restrict__ out)        // [32, 5] f32
{
    const int b    = blockIdx.x;    // one block per batch row
    const int t    = threadIdx.x;
    const int wave = t >> 6;
    const int lane = t & 63;

    __shared__ int   xs[NHITS * 3];       // 600 ints, staged coalesced
    __shared__ int   flat[NHITS];
    __shared__ float wsum[4][OUT_N];

    // coalesced stage of this row's indices: 600 ints = 150 int4 (row base is 2400B, 16B-aligned)
    const int4* xrow = (const int4*)(x + b * NHITS * 3);
    if (t < 150) ((int4*)xs)[t] = xrow[t];
    __syncthreads();

    if (t < NHITS) flat[t] = xs[3 * t + 1] * D1 + xs[3 * t + 2];
    __syncthreads();

    float v0 = 0.f, v1 = 0.f, v2 = 0.f, v3 = 0.f, v4 = 0.f;
    if (t < NHITS) {
        const int f = flat[t];
        // dedup: first-occurrence wins. Uniform loop -> LDS broadcast reads, pipelined.
        int dup = 0;
        #pragma unroll 8
        for (int j = 0; j < NHITS; ++j) {
            const int fj = flat[j];
            dup |= (int)((j < t) & (fj == f));
        }
        if (!dup) {
            const float* w = W + (size_t)f * OUT_N;
            v0 = w[0]; v1 = w[1]; v2 = w[2]; v3 = w[3]; v4 = w[4];
        }
    }

    // 64-lane shuffle reduction per output, then per-wave partial to LDS
    float vv[OUT_N] = {v0, v1, v2, v3, v4};
    #pragma unroll
    for (int o = 0; o < OUT_N; ++o) {
        float s = vv[o];
        #pragma unroll
        for (int off = 32; off >= 1; off >>= 1) s += __shfl_down(s, off);
        if (lane == 0) wsum[wave][o] = s;
    }
    __syncthreads();

    if (t < OUT_N) {
        out[b * OUT_N + t] = wsum[0][t] + wsum[1][t] + wsum[2][t] + wsum[3][t] + bias[t];
    }
}

extern "C" void kernel_launch(void* const* d_in, const int* in_sizes, int n_in,
                              void* d_out, int out_size, void* d_ws, size_t ws_size,
                              hipStream_t stream) {
    const int*   x    = (const int*)d_in[0];     // [32,200,3]
    const float* W    = (const float*)d_in[1];   // [2150400,5]
    const float* bias = (const float*)d_in[2];   // [5]
    float*       out  = (float*)d_out;           // [32,5]

    prtnn_gather_kernel<<<B_ROWS, 256, 0, stream>>>(x, W, bias, out);
}